// Round 7
// baseline (139.948 us; speedup 1.0000x reference)
//
#include <hip/hip_runtime.h>
#include <hip/hip_bf16.h>
#include <math.h>

#define N 4096

// K_A: fused ascending rank of preds + softmax matvec -> y.  256 blocks x 256.
// Block b owns preds[16b..16b+16); computes each one's global rank by counting,
// then evaluates that softmax row (one row per wave): y[rank] = sm(row).target.
// Row max of the logits is exactly 0 (diagonal term), so single-pass exp is
// numerically identical to jax's subtract-max softmax.
__global__ void k_A(const float* __restrict__ preds, const float* __restrict__ target,
                    float* __restrict__ y) {
    __shared__ __align__(16) float sp[N];
    __shared__ __align__(16) float st[N];
    __shared__ int part[16][17];
    __shared__ int rks[16];
    int tid = threadIdx.x;
    int b = blockIdx.x;
    int lane = tid & 63, wid = tid >> 6;
    for (int m = 0; m < 16; m++) {
        int idx = tid + 256 * m;
        sp[idx] = preds[idx];
        st[idx] = target[idx];
    }
    __syncthreads();
    {
        int eloc = tid & 15, slice = tid >> 4;
        int i0 = b * 16 + eloc;
        float v = sp[i0];
        int cnt = 0;
        const float4* sp4 = (const float4*)sp;
        for (int it = 0; it < 64; it++) {
            int q = slice * 64 + ((it + slice) & 63); // stagger across banks
            float4 a = sp4[q];
            int j = q * 4;
            cnt += (a.x < v) || (a.x == v && (j + 0) < i0);
            cnt += (a.y < v) || (a.y == v && (j + 1) < i0);
            cnt += (a.z < v) || (a.z == v && (j + 2) < i0);
            cnt += (a.w < v) || (a.w == v && (j + 3) < i0);
        }
        part[eloc][slice] = cnt;
    }
    __syncthreads();
    if (tid < 16) {
        int rr = 0;
        #pragma unroll
        for (int q = 0; q < 16; q++) rr += part[tid][q];
        rks[tid] = rr;
    }
    __syncthreads();
    const float4* sp4 = (const float4*)sp;
    const float4* st4 = (const float4*)st;
    #pragma unroll
    for (int t = 0; t < 4; t++) {
        int rr = 4 * t + wid;               // owned element 0..15
        float xv = sp[b * 16 + rr];
        float Z = 0.f, Nm = 0.f;
        #pragma unroll 4
        for (int m = 0; m < 16; m++) {
            int q = lane + 64 * m;          // float4 index; conflict-free b128
            float4 p4 = sp4[q];
            float4 t4 = st4[q];
            float d0 = xv - p4.x, d1 = xv - p4.y, d2 = xv - p4.z, d3 = xv - p4.w;
            float e0 = __expf(-100.0f * d0 * d0);
            float e1 = __expf(-100.0f * d1 * d1);
            float e2 = __expf(-100.0f * d2 * d2);
            float e3 = __expf(-100.0f * d3 * d3);
            Z += (e0 + e1) + (e2 + e3);
            Nm += e0 * t4.x + e1 * t4.y + e2 * t4.z + e3 * t4.w;
        }
        #pragma unroll
        for (int d = 32; d; d >>= 1) {
            Z += __shfl_down(Z, d);
            Nm += __shfl_down(Nm, d);
        }
        if (lane == 0) y[rks[rr]] = Nm / Z;
    }
}

// K_B: descending stable rank of y; s[r] = y*100, perm[r] = i.  256 blocks x 256.
__global__ void k_B(const float* __restrict__ y, float* __restrict__ s_out,
                    int* __restrict__ perm_out) {
    __shared__ __align__(16) float sy[N];
    __shared__ int part[16][17];
    int tid = threadIdx.x;
    int b = blockIdx.x;
    for (int m = 0; m < 16; m++) sy[tid + 256 * m] = y[tid + 256 * m];
    __syncthreads();
    int eloc = tid & 15;
    int slice = tid >> 4;
    int i = b * 16 + eloc;
    float v = sy[i];
    int cnt = 0;
    const float4* sy4 = (const float4*)sy;
    for (int it = 0; it < 64; it++) {
        int q = slice * 64 + ((it + slice) & 63);
        float4 a = sy4[q];
        int j = q * 4;
        cnt += (a.x > v) || (a.x == v && (j + 0) < i);
        cnt += (a.y > v) || (a.y == v && (j + 1) < i);
        cnt += (a.z > v) || (a.z == v && (j + 2) < i);
        cnt += (a.w > v) || (a.w == v && (j + 3) < i);
    }
    part[eloc][slice] = cnt;
    __syncthreads();
    if (tid < 16) {
        int r = 0;
        #pragma unroll
        for (int q = 0; q < 16; q++) r += part[tid][q];
        int i2 = b * 16 + tid;
        s_out[r] = sy[i2] * 100.0f;
        perm_out[r] = i2;
    }
}

// K_C: fused f64 cumsum of z[t]=(N-t)-s[t] + isotonic min-max scan.
// Block b covers rows j in [16b,16b+16); writes per-block column-max P[b][i]
// only for i >= 16b (columns below are never valid candidates).
__global__ void k_C(const float* __restrict__ s, float* __restrict__ P) {
    __shared__ __align__(16) float mArr[4][256];
    __shared__ float incl[4][257];
    __shared__ double cj[16];
    __shared__ double wsum[4];
    int tid = threadIdx.x;
    int b = blockIdx.x;
    int j0 = b * 16;
    int kbase = tid * 16;
    int lane = tid & 63, wid = tid >> 6;
    double loc[16];
    {
        const float4* s4 = (const float4*)s;
        double tot = 0.0;
        #pragma unroll
        for (int q = 0; q < 4; q++) {
            float4 a = s4[tid * 4 + q];
            int t0 = kbase + q * 4;
            tot += (double)(N - (t0 + 0)) - (double)a.x; loc[q * 4 + 0] = tot;
            tot += (double)(N - (t0 + 1)) - (double)a.y; loc[q * 4 + 1] = tot;
            tot += (double)(N - (t0 + 2)) - (double)a.z; loc[q * 4 + 2] = tot;
            tot += (double)(N - (t0 + 3)) - (double)a.w; loc[q * 4 + 3] = tot;
        }
        double w = tot;
        #pragma unroll
        for (int d = 1; d < 64; d <<= 1) {
            double o = __shfl_up(w, d);
            if (lane >= d) w += o;
        }
        if (lane == 63) wsum[wid] = w;
        __syncthreads();
        double base = 0.0;
        #pragma unroll
        for (int q = 0; q < 4; q++) if (q < wid) base += wsum[q];
        double excl = base + (w - tot);
        #pragma unroll
        for (int e = 0; e < 16; e++) loc[e] += excl; // loc[e] = cs[kbase+1+e]
        if (tid == b) {                              // owns cs[j0..j0+16)
            cj[0] = excl;
            #pragma unroll
            for (int m = 1; m < 16; m++) cj[m] = loc[m - 1];
        }
    }
    __syncthreads();
    float vloc[16];
    #pragma unroll
    for (int e = 0; e < 16; e++) vloc[e] = -INFINITY;
    float ls[4][16];
    for (int grp = 0; grp < 4; grp++) {
        #pragma unroll
        for (int rq = 0; rq < 4; rq++) {
            int j = j0 + grp * 4 + rq;
            double csj = cj[grp * 4 + rq];
            float run = INFINITY;
            #pragma unroll
            for (int e = 15; e >= 0; e--) {
                int k = kbase + e;
                float f = INFINITY;
                if (k >= j) f = (float)(loc[e] - csj) * __builtin_amdgcn_rcpf((float)(k - j + 1));
                run = fminf(f, run);
                ls[rq][e] = run;
            }
            mArr[rq][tid] = run;
        }
        __syncthreads();
        {
            int w = tid >> 6, l = tid & 63;
            float4 xv = ((const float4*)mArr[w])[l];
            float s3 = xv.w;
            float s2 = fminf(xv.z, s3);
            float s1 = fminf(xv.y, s2);
            float s0 = fminf(xv.x, s1);
            float t = s0;
            #pragma unroll
            for (int d = 1; d < 64; d <<= 1) {
                float o = __shfl_down(t, d);
                if (l + d < 64) t = fminf(t, o);
            }
            float after = __shfl_down(t, 1);
            if (l == 63) after = INFINITY;
            incl[w][4 * l + 0] = fminf(s0, after);
            incl[w][4 * l + 1] = fminf(s1, after);
            incl[w][4 * l + 2] = fminf(s2, after);
            incl[w][4 * l + 3] = fminf(s3, after);
            if (l == 0) incl[w][256] = INFINITY;
        }
        __syncthreads();
        #pragma unroll
        for (int rq = 0; rq < 4; rq++) {
            int j = j0 + grp * 4 + rq;
            float aft = incl[rq][tid + 1];
            #pragma unroll
            for (int e = 0; e < 16; e++) {
                int i = kbase + e;
                float sv = fminf(ls[rq][e], aft);
                if (i >= j) vloc[e] = fmaxf(vloc[e], sv);
            }
        }
        __syncthreads();
    }
    if (tid >= b) {   // thread tid owns columns [16tid,16tid+16); valid iff >= j0
        float4* P4 = (float4*)(P + (size_t)b * N);
        #pragma unroll
        for (int q = 0; q < 4; q++)
            P4[tid * 4 + q] = make_float4(vloc[4 * q + 0], vloc[4 * q + 1],
                                          vloc[4 * q + 2], vloc[4 * q + 3]);
    }
}

// K_reduce: T[i] = max_{b<=blk} P[b][i]; r[perm[i]] = s[i] + T[i]. 256 blocks x 256.
// Only partials b <= blockIdx.x contain candidates for these columns
// (floor(i/16) == blockIdx.x for every lane -> wave-uniform bound).
__global__ void k_reduce(const float* __restrict__ P, const float* __restrict__ s,
                         const int* __restrict__ perm, float* __restrict__ r) {
    __shared__ float part[16][17];
    int tid = threadIdx.x;
    int col = tid & 15;
    int slice = tid >> 4;
    int blk = blockIdx.x;
    int i = blk * 16 + col;
    float m = -INFINITY;
    #pragma unroll
    for (int q = 0; q < 16; q++) {
        int b = slice * 16 + q;
        if (b <= blk) m = fmaxf(m, P[(size_t)b * N + i]);
    }
    part[col][slice] = m;
    __syncthreads();
    if (tid < 16) {
        float T = -INFINITY;
        #pragma unroll
        for (int q = 0; q < 16; q++) T = fmaxf(T, part[tid][q]);
        int i2 = blk * 16 + tid;
        r[perm[i2]] = s[i2] + T;
    }
}

// K_finish2: diff-sum over r in original order; emit out. 1 block x 256.
__global__ void k_finish2(const float* __restrict__ r, float* __restrict__ out) {
    __shared__ double red[4];
    int tid = threadIdx.x;
    const float4* r4 = (const float4*)r;
    float a[16];
    #pragma unroll
    for (int q = 0; q < 4; q++) {
        float4 x = r4[tid * 4 + q];
        a[q * 4 + 0] = x.x; a[q * 4 + 1] = x.y; a[q * 4 + 2] = x.z; a[q * 4 + 3] = x.w;
    }
    float extra = (tid < 255) ? r[tid * 16 + 16] : 0.0f;
    double acc = 0.0;
    #pragma unroll
    for (int e = 0; e < 16; e++) {
        int d = tid * 16 + e;
        float nxt = (e < 15) ? a[e + 1] : extra;
        if (d < N - 1) acc += fabs((double)nxt - (double)a[e]);
    }
    #pragma unroll
    for (int dd = 32; dd; dd >>= 1) acc += __shfl_down(acc, dd);
    if ((tid & 63) == 0) red[tid >> 6] = acc;
    __syncthreads();
    if (tid == 0) {
        double ds = red[0] + red[1] + red[2] + red[3];
        double xi = 1.0 - 3.0 * ds / ((double)N * (double)N - 1.0);
        out[0] = (float)(-1.0 * xi);  // loss = -WEIGHT * xi
        out[1] = (float)xi;
    }
}

extern "C" void kernel_launch(void* const* d_in, const int* in_sizes, int n_in,
                              void* d_out, int out_size, void* d_ws, size_t ws_size,
                              hipStream_t stream) {
    const float* preds  = (const float*)d_in[0];
    const float* target = (const float*)d_in[1];
    float* out = (float*)d_out;

    char* ws = (char*)d_ws;
    float* y    = (float*)(ws);            // 16 KB
    float* s    = (float*)(ws + 16384);    // 16 KB
    int*   perm = (int*)(ws + 32768);      // 16 KB
    float* r    = (float*)(ws + 49152);    // 16 KB
    float* P    = (float*)(ws + 81920);    // 4 MB

    k_A<<<256, 256, 0, stream>>>(preds, target, y);
    k_B<<<256, 256, 0, stream>>>(y, s, perm);
    k_C<<<256, 256, 0, stream>>>(s, P);
    k_reduce<<<256, 256, 0, stream>>>(P, s, perm, r);
    k_finish2<<<1, 256, 0, stream>>>(r, out);
}

// Round 8
// 119.482 us; speedup vs baseline: 1.1713x; 1.1713x over previous
//
#include <hip/hip_runtime.h>
#include <hip/hip_bf16.h>
#include <math.h>

#define N 4096

// All kernels: 256 blocks x 256 threads = 1 block/CU. __launch_bounds__(256,1)
// lifts the compiler's default 8-wave/SIMD occupancy target (which caps VGPRs
// at 64 and forced k_C to spill ~9 MB/dispatch to scratch) to 512 VGPRs.

// K_A: fused ascending rank of preds + softmax matvec -> y.
__global__ __launch_bounds__(256, 1)
void k_A(const float* __restrict__ preds, const float* __restrict__ target,
         float* __restrict__ y) {
    __shared__ __align__(16) float sp[N];
    __shared__ __align__(16) float st[N];
    __shared__ int part[16][17];
    __shared__ int rks[16];
    int tid = threadIdx.x;
    int b = blockIdx.x;
    int lane = tid & 63, wid = tid >> 6;
    for (int m = 0; m < 16; m++) {
        int idx = tid + 256 * m;
        sp[idx] = preds[idx];
        st[idx] = target[idx];
    }
    __syncthreads();
    {
        int eloc = tid & 15, slice = tid >> 4;
        int i0 = b * 16 + eloc;
        float v = sp[i0];
        int cnt = 0;
        const float4* sp4 = (const float4*)sp;
        for (int it = 0; it < 64; it++) {
            int q = slice * 64 + ((it + slice) & 63); // stagger across banks
            float4 a = sp4[q];
            int j = q * 4;
            cnt += (a.x < v) || (a.x == v && (j + 0) < i0);
            cnt += (a.y < v) || (a.y == v && (j + 1) < i0);
            cnt += (a.z < v) || (a.z == v && (j + 2) < i0);
            cnt += (a.w < v) || (a.w == v && (j + 3) < i0);
        }
        part[eloc][slice] = cnt;
    }
    __syncthreads();
    if (tid < 16) {
        int rr = 0;
        #pragma unroll
        for (int q = 0; q < 16; q++) rr += part[tid][q];
        rks[tid] = rr;
    }
    __syncthreads();
    const float4* sp4 = (const float4*)sp;
    const float4* st4 = (const float4*)st;
    #pragma unroll
    for (int t = 0; t < 4; t++) {
        int rr = 4 * t + wid;               // owned element 0..15
        float xv = sp[b * 16 + rr];
        float Z = 0.f, Nm = 0.f;
        #pragma unroll 4
        for (int m = 0; m < 16; m++) {
            int q = lane + 64 * m;          // float4 index; conflict-free b128
            float4 p4 = sp4[q];
            float4 t4 = st4[q];
            float d0 = xv - p4.x, d1 = xv - p4.y, d2 = xv - p4.z, d3 = xv - p4.w;
            float e0 = __expf(-100.0f * d0 * d0);
            float e1 = __expf(-100.0f * d1 * d1);
            float e2 = __expf(-100.0f * d2 * d2);
            float e3 = __expf(-100.0f * d3 * d3);
            Z += (e0 + e1) + (e2 + e3);
            Nm += e0 * t4.x + e1 * t4.y + e2 * t4.z + e3 * t4.w;
        }
        #pragma unroll
        for (int d = 32; d; d >>= 1) {
            Z += __shfl_down(Z, d);
            Nm += __shfl_down(Nm, d);
        }
        if (lane == 0) y[rks[rr]] = Nm / Z;
    }
}

// K_B: descending stable rank of y; s[r] = y*100, perm[r] = i.
__global__ __launch_bounds__(256, 1)
void k_B(const float* __restrict__ y, float* __restrict__ s_out,
         int* __restrict__ perm_out) {
    __shared__ __align__(16) float sy[N];
    __shared__ int part[16][17];
    int tid = threadIdx.x;
    int b = blockIdx.x;
    for (int m = 0; m < 16; m++) sy[tid + 256 * m] = y[tid + 256 * m];
    __syncthreads();
    int eloc = tid & 15;
    int slice = tid >> 4;
    int i = b * 16 + eloc;
    float v = sy[i];
    int cnt = 0;
    const float4* sy4 = (const float4*)sy;
    for (int it = 0; it < 64; it++) {
        int q = slice * 64 + ((it + slice) & 63);
        float4 a = sy4[q];
        int j = q * 4;
        cnt += (a.x > v) || (a.x == v && (j + 0) < i);
        cnt += (a.y > v) || (a.y == v && (j + 1) < i);
        cnt += (a.z > v) || (a.z == v && (j + 2) < i);
        cnt += (a.w > v) || (a.w == v && (j + 3) < i);
    }
    part[eloc][slice] = cnt;
    __syncthreads();
    if (tid < 16) {
        int r = 0;
        #pragma unroll
        for (int q = 0; q < 16; q++) r += part[tid][q];
        int i2 = b * 16 + tid;
        s_out[r] = sy[i2] * 100.0f;
        perm_out[r] = i2;
    }
}

// K_C: fused f64 cumsum of z[t]=(N-t)-s[t] + isotonic min-max scan.
// Block b covers rows j in [16b,16b+16); writes per-block column-max P[b][i]
// only for i >= 16b (columns below are never valid candidates).
__global__ __launch_bounds__(256, 1)
void k_C(const float* __restrict__ s, float* __restrict__ P) {
    __shared__ __align__(16) float mArr[4][256];
    __shared__ float incl[4][257];
    __shared__ double cj[16];
    __shared__ double wsum[4];
    int tid = threadIdx.x;
    int b = blockIdx.x;
    int j0 = b * 16;
    int kbase = tid * 16;
    int lane = tid & 63, wid = tid >> 6;
    double loc[16];
    {
        const float4* s4 = (const float4*)s;
        double tot = 0.0;
        #pragma unroll
        for (int q = 0; q < 4; q++) {
            float4 a = s4[tid * 4 + q];
            int t0 = kbase + q * 4;
            tot += (double)(N - (t0 + 0)) - (double)a.x; loc[q * 4 + 0] = tot;
            tot += (double)(N - (t0 + 1)) - (double)a.y; loc[q * 4 + 1] = tot;
            tot += (double)(N - (t0 + 2)) - (double)a.z; loc[q * 4 + 2] = tot;
            tot += (double)(N - (t0 + 3)) - (double)a.w; loc[q * 4 + 3] = tot;
        }
        double w = tot;
        #pragma unroll
        for (int d = 1; d < 64; d <<= 1) {
            double o = __shfl_up(w, d);
            if (lane >= d) w += o;
        }
        if (lane == 63) wsum[wid] = w;
        __syncthreads();
        double base = 0.0;
        #pragma unroll
        for (int q = 0; q < 4; q++) if (q < wid) base += wsum[q];
        double excl = base + (w - tot);
        #pragma unroll
        for (int e = 0; e < 16; e++) loc[e] += excl; // loc[e] = cs[kbase+1+e]
        if (tid == b) {                              // owns cs[j0..j0+16)
            cj[0] = excl;
            #pragma unroll
            for (int m = 1; m < 16; m++) cj[m] = loc[m - 1];
        }
    }
    __syncthreads();
    float vloc[16];
    #pragma unroll
    for (int e = 0; e < 16; e++) vloc[e] = -INFINITY;
    float ls[4][16];
    for (int grp = 0; grp < 4; grp++) {
        #pragma unroll
        for (int rq = 0; rq < 4; rq++) {
            int j = j0 + grp * 4 + rq;
            double csj = cj[grp * 4 + rq];
            float run = INFINITY;
            #pragma unroll
            for (int e = 15; e >= 0; e--) {
                int k = kbase + e;
                float f = INFINITY;
                if (k >= j) f = (float)(loc[e] - csj) * __builtin_amdgcn_rcpf((float)(k - j + 1));
                run = fminf(f, run);
                ls[rq][e] = run;
            }
            mArr[rq][tid] = run;
        }
        __syncthreads();
        {
            int w = tid >> 6, l = tid & 63;
            float4 xv = ((const float4*)mArr[w])[l];
            float s3 = xv.w;
            float s2 = fminf(xv.z, s3);
            float s1 = fminf(xv.y, s2);
            float s0 = fminf(xv.x, s1);
            float t = s0;
            #pragma unroll
            for (int d = 1; d < 64; d <<= 1) {
                float o = __shfl_down(t, d);
                if (l + d < 64) t = fminf(t, o);
            }
            float after = __shfl_down(t, 1);
            if (l == 63) after = INFINITY;
            incl[w][4 * l + 0] = fminf(s0, after);
            incl[w][4 * l + 1] = fminf(s1, after);
            incl[w][4 * l + 2] = fminf(s2, after);
            incl[w][4 * l + 3] = fminf(s3, after);
            if (l == 0) incl[w][256] = INFINITY;
        }
        __syncthreads();
        #pragma unroll
        for (int rq = 0; rq < 4; rq++) {
            int j = j0 + grp * 4 + rq;
            float aft = incl[rq][tid + 1];
            #pragma unroll
            for (int e = 0; e < 16; e++) {
                int i = kbase + e;
                float sv = fminf(ls[rq][e], aft);
                if (i >= j) vloc[e] = fmaxf(vloc[e], sv);
            }
        }
        __syncthreads();
    }
    if (tid >= b) {   // thread tid owns columns [16tid,16tid+16); valid iff >= j0
        float4* P4 = (float4*)(P + (size_t)b * N);
        #pragma unroll
        for (int q = 0; q < 4; q++)
            P4[tid * 4 + q] = make_float4(vloc[4 * q + 0], vloc[4 * q + 1],
                                          vloc[4 * q + 2], vloc[4 * q + 3]);
    }
}

// K_reduce: T[i] = max_{b<=blk} P[b][i]; r[perm[i]] = s[i] + T[i].
__global__ __launch_bounds__(256, 1)
void k_reduce(const float* __restrict__ P, const float* __restrict__ s,
              const int* __restrict__ perm, float* __restrict__ r) {
    __shared__ float part[16][17];
    int tid = threadIdx.x;
    int col = tid & 15;
    int slice = tid >> 4;
    int blk = blockIdx.x;
    int i = blk * 16 + col;
    float m = -INFINITY;
    #pragma unroll
    for (int q = 0; q < 16; q++) {
        int b = slice * 16 + q;
        if (b <= blk) m = fmaxf(m, P[(size_t)b * N + i]);
    }
    part[col][slice] = m;
    __syncthreads();
    if (tid < 16) {
        float T = -INFINITY;
        #pragma unroll
        for (int q = 0; q < 16; q++) T = fmaxf(T, part[tid][q]);
        int i2 = blk * 16 + tid;
        r[perm[i2]] = s[i2] + T;
    }
}

// K_finish2: diff-sum over r in original order; emit out. 1 block x 256.
__global__ __launch_bounds__(256, 1)
void k_finish2(const float* __restrict__ r, float* __restrict__ out) {
    __shared__ double red[4];
    int tid = threadIdx.x;
    const float4* r4 = (const float4*)r;
    float a[16];
    #pragma unroll
    for (int q = 0; q < 4; q++) {
        float4 x = r4[tid * 4 + q];
        a[q * 4 + 0] = x.x; a[q * 4 + 1] = x.y; a[q * 4 + 2] = x.z; a[q * 4 + 3] = x.w;
    }
    float extra = (tid < 255) ? r[tid * 16 + 16] : 0.0f;
    double acc = 0.0;
    #pragma unroll
    for (int e = 0; e < 16; e++) {
        int d = tid * 16 + e;
        float nxt = (e < 15) ? a[e + 1] : extra;
        if (d < N - 1) acc += fabs((double)nxt - (double)a[e]);
    }
    #pragma unroll
    for (int dd = 32; dd; dd >>= 1) acc += __shfl_down(acc, dd);
    if ((tid & 63) == 0) red[tid >> 6] = acc;
    __syncthreads();
    if (tid == 0) {
        double ds = red[0] + red[1] + red[2] + red[3];
        double xi = 1.0 - 3.0 * ds / ((double)N * (double)N - 1.0);
        out[0] = (float)(-1.0 * xi);  // loss = -WEIGHT * xi
        out[1] = (float)xi;
    }
}

extern "C" void kernel_launch(void* const* d_in, const int* in_sizes, int n_in,
                              void* d_out, int out_size, void* d_ws, size_t ws_size,
                              hipStream_t stream) {
    const float* preds  = (const float*)d_in[0];
    const float* target = (const float*)d_in[1];
    float* out = (float*)d_out;

    char* ws = (char*)d_ws;
    float* y    = (float*)(ws);            // 16 KB
    float* s    = (float*)(ws + 16384);    // 16 KB
    int*   perm = (int*)(ws + 32768);      // 16 KB
    float* r    = (float*)(ws + 49152);    // 16 KB
    float* P    = (float*)(ws + 81920);    // 4 MB

    k_A<<<256, 256, 0, stream>>>(preds, target, y);
    k_B<<<256, 256, 0, stream>>>(y, s, perm);
    k_C<<<256, 256, 0, stream>>>(s, P);
    k_reduce<<<256, 256, 0, stream>>>(P, s, perm, r);
    k_finish2<<<1, 256, 0, stream>>>(r, out);
}

// Round 9
// 107.950 us; speedup vs baseline: 1.2964x; 1.1068x over previous
//
#include <hip/hip_runtime.h>
#include <hip/hip_bf16.h>
#include <math.h>

#define N 4096

// All kernels: 256 blocks x 256 threads = 1 block/CU. __launch_bounds__(256,1)
// lifts the compiler's default 8-wave/SIMD occupancy target (which caps VGPRs
// at 64 and forced k_C to spill ~9 MB/dispatch to scratch) to 512 VGPRs.

// K_A: fused ascending-rank + softmax matvec -> y, single pass.
// For each owned element (16/block, one row per wave per t-iter), the softmax
// scan over all N already touches every preds[j]; the rank count rides along:
// cnt = #{j : preds[j] < v || (== v && j < i0)}. Lane 0 stores y[cnt] = Nm/Z.
// Row max of the logits is exactly 0 (diagonal term), so single-pass exp is
// numerically identical to jax's subtract-max softmax.
__global__ __launch_bounds__(256, 1)
void k_A(const float* __restrict__ preds, const float* __restrict__ target,
         float* __restrict__ y) {
    __shared__ __align__(16) float4 sp4[N / 4];
    __shared__ __align__(16) float4 st4[N / 4];
    int tid = threadIdx.x;
    int b = blockIdx.x;
    int lane = tid & 63, wid = tid >> 6;
    const float4* gp = (const float4*)preds;
    const float4* gt = (const float4*)target;
    #pragma unroll
    for (int m = 0; m < 4; m++) {
        sp4[tid + 256 * m] = gp[tid + 256 * m];
        st4[tid + 256 * m] = gt[tid + 256 * m];
    }
    __syncthreads();
    const float* sp = (const float*)sp4;
    #pragma unroll
    for (int t = 0; t < 4; t++) {
        int rr = 4 * t + wid;               // owned element 0..15
        int i0 = b * 16 + rr;
        float xv = sp[i0];
        float Z = 0.f, Nm = 0.f;
        int cnt = 0;
        #pragma unroll 4
        for (int m = 0; m < 16; m++) {
            int q = lane + 64 * m;          // float4 index; conflict-free b128
            float4 p4 = sp4[q];
            float4 t4 = st4[q];
            int j = q * 4;
            float d0 = xv - p4.x, d1 = xv - p4.y, d2 = xv - p4.z, d3 = xv - p4.w;
            float e0 = __expf(-100.0f * d0 * d0);
            float e1 = __expf(-100.0f * d1 * d1);
            float e2 = __expf(-100.0f * d2 * d2);
            float e3 = __expf(-100.0f * d3 * d3);
            Z += (e0 + e1) + (e2 + e3);
            Nm += e0 * t4.x + e1 * t4.y + e2 * t4.z + e3 * t4.w;
            cnt += (p4.x < xv) || (p4.x == xv && (j + 0) < i0);
            cnt += (p4.y < xv) || (p4.y == xv && (j + 1) < i0);
            cnt += (p4.z < xv) || (p4.z == xv && (j + 2) < i0);
            cnt += (p4.w < xv) || (p4.w == xv && (j + 3) < i0);
        }
        #pragma unroll
        for (int d = 32; d; d >>= 1) {
            Z += __shfl_down(Z, d);
            Nm += __shfl_down(Nm, d);
            cnt += __shfl_down(cnt, d);
        }
        if (lane == 0) y[cnt] = Nm / Z;
    }
}

// K_B: descending stable rank of y; s[r] = y*100, perm[r] = i.
__global__ __launch_bounds__(256, 1)
void k_B(const float* __restrict__ y, float* __restrict__ s_out,
         int* __restrict__ perm_out) {
    __shared__ __align__(16) float sy[N];
    __shared__ int part[16][17];
    int tid = threadIdx.x;
    int b = blockIdx.x;
    for (int m = 0; m < 16; m++) sy[tid + 256 * m] = y[tid + 256 * m];
    __syncthreads();
    int eloc = tid & 15;
    int slice = tid >> 4;
    int i = b * 16 + eloc;
    float v = sy[i];
    int cnt = 0;
    const float4* sy4 = (const float4*)sy;
    for (int it = 0; it < 64; it++) {
        int q = slice * 64 + ((it + slice) & 63);
        float4 a = sy4[q];
        int j = q * 4;
        cnt += (a.x > v) || (a.x == v && (j + 0) < i);
        cnt += (a.y > v) || (a.y == v && (j + 1) < i);
        cnt += (a.z > v) || (a.z == v && (j + 2) < i);
        cnt += (a.w > v) || (a.w == v && (j + 3) < i);
    }
    part[eloc][slice] = cnt;
    __syncthreads();
    if (tid < 16) {
        int r = 0;
        #pragma unroll
        for (int q = 0; q < 16; q++) r += part[tid][q];
        int i2 = b * 16 + tid;
        s_out[r] = sy[i2] * 100.0f;
        perm_out[r] = i2;
    }
}

// K_C: fused f64 cumsum of z[t]=(N-t)-s[t] + isotonic min-max scan.
// Block b covers rows j in [16b,16b+16); writes per-block column-max P[b][i]
// only for i >= 16b (columns below are never valid candidates).
__global__ __launch_bounds__(256, 1)
void k_C(const float* __restrict__ s, float* __restrict__ P) {
    __shared__ __align__(16) float mArr[4][256];
    __shared__ float incl[4][257];
    __shared__ double cj[16];
    __shared__ double wsum[4];
    int tid = threadIdx.x;
    int b = blockIdx.x;
    int j0 = b * 16;
    int kbase = tid * 16;
    int lane = tid & 63, wid = tid >> 6;
    double loc[16];
    {
        const float4* s4 = (const float4*)s;
        double tot = 0.0;
        #pragma unroll
        for (int q = 0; q < 4; q++) {
            float4 a = s4[tid * 4 + q];
            int t0 = kbase + q * 4;
            tot += (double)(N - (t0 + 0)) - (double)a.x; loc[q * 4 + 0] = tot;
            tot += (double)(N - (t0 + 1)) - (double)a.y; loc[q * 4 + 1] = tot;
            tot += (double)(N - (t0 + 2)) - (double)a.z; loc[q * 4 + 2] = tot;
            tot += (double)(N - (t0 + 3)) - (double)a.w; loc[q * 4 + 3] = tot;
        }
        double w = tot;
        #pragma unroll
        for (int d = 1; d < 64; d <<= 1) {
            double o = __shfl_up(w, d);
            if (lane >= d) w += o;
        }
        if (lane == 63) wsum[wid] = w;
        __syncthreads();
        double base = 0.0;
        #pragma unroll
        for (int q = 0; q < 4; q++) if (q < wid) base += wsum[q];
        double excl = base + (w - tot);
        #pragma unroll
        for (int e = 0; e < 16; e++) loc[e] += excl; // loc[e] = cs[kbase+1+e]
        if (tid == b) {                              // owns cs[j0..j0+16)
            cj[0] = excl;
            #pragma unroll
            for (int m = 1; m < 16; m++) cj[m] = loc[m - 1];
        }
    }
    __syncthreads();
    float vloc[16];
    #pragma unroll
    for (int e = 0; e < 16; e++) vloc[e] = -INFINITY;
    float ls[4][16];
    for (int grp = 0; grp < 4; grp++) {
        #pragma unroll
        for (int rq = 0; rq < 4; rq++) {
            int j = j0 + grp * 4 + rq;
            double csj = cj[grp * 4 + rq];
            float run = INFINITY;
            #pragma unroll
            for (int e = 15; e >= 0; e--) {
                int k = kbase + e;
                float f = INFINITY;
                if (k >= j) f = (float)(loc[e] - csj) * __builtin_amdgcn_rcpf((float)(k - j + 1));
                run = fminf(f, run);
                ls[rq][e] = run;
            }
            mArr[rq][tid] = run;
        }
        __syncthreads();
        {
            int w = tid >> 6, l = tid & 63;
            float4 xv = ((const float4*)mArr[w])[l];
            float s3 = xv.w;
            float s2 = fminf(xv.z, s3);
            float s1 = fminf(xv.y, s2);
            float s0 = fminf(xv.x, s1);
            float t = s0;
            #pragma unroll
            for (int d = 1; d < 64; d <<= 1) {
                float o = __shfl_down(t, d);
                if (l + d < 64) t = fminf(t, o);
            }
            float after = __shfl_down(t, 1);
            if (l == 63) after = INFINITY;
            incl[w][4 * l + 0] = fminf(s0, after);
            incl[w][4 * l + 1] = fminf(s1, after);
            incl[w][4 * l + 2] = fminf(s2, after);
            incl[w][4 * l + 3] = fminf(s3, after);
            if (l == 0) incl[w][256] = INFINITY;
        }
        __syncthreads();
        #pragma unroll
        for (int rq = 0; rq < 4; rq++) {
            int j = j0 + grp * 4 + rq;
            float aft = incl[rq][tid + 1];
            #pragma unroll
            for (int e = 0; e < 16; e++) {
                int i = kbase + e;
                float sv = fminf(ls[rq][e], aft);
                if (i >= j) vloc[e] = fmaxf(vloc[e], sv);
            }
        }
        __syncthreads();
    }
    if (tid >= b) {   // thread tid owns columns [16tid,16tid+16); valid iff >= j0
        float4* P4 = (float4*)(P + (size_t)b * N);
        #pragma unroll
        for (int q = 0; q < 4; q++)
            P4[tid * 4 + q] = make_float4(vloc[4 * q + 0], vloc[4 * q + 1],
                                          vloc[4 * q + 2], vloc[4 * q + 3]);
    }
}

// K_reduce: T[i] = max_{b<=blk} P[b][i]; r[perm[i]] = s[i] + T[i].
__global__ __launch_bounds__(256, 1)
void k_reduce(const float* __restrict__ P, const float* __restrict__ s,
              const int* __restrict__ perm, float* __restrict__ r) {
    __shared__ float part[16][17];
    int tid = threadIdx.x;
    int col = tid & 15;
    int slice = tid >> 4;
    int blk = blockIdx.x;
    int i = blk * 16 + col;
    float m = -INFINITY;
    #pragma unroll
    for (int q = 0; q < 16; q++) {
        int b = slice * 16 + q;
        if (b <= blk) m = fmaxf(m, P[(size_t)b * N + i]);
    }
    part[col][slice] = m;
    __syncthreads();
    if (tid < 16) {
        float T = -INFINITY;
        #pragma unroll
        for (int q = 0; q < 16; q++) T = fmaxf(T, part[tid][q]);
        int i2 = blk * 16 + tid;
        r[perm[i2]] = s[i2] + T;
    }
}

// K_finish2: diff-sum over r in original order; emit out. 1 block x 256.
__global__ __launch_bounds__(256, 1)
void k_finish2(const float* __restrict__ r, float* __restrict__ out) {
    __shared__ double red[4];
    int tid = threadIdx.x;
    const float4* r4 = (const float4*)r;
    float a[16];
    #pragma unroll
    for (int q = 0; q < 4; q++) {
        float4 x = r4[tid * 4 + q];
        a[q * 4 + 0] = x.x; a[q * 4 + 1] = x.y; a[q * 4 + 2] = x.z; a[q * 4 + 3] = x.w;
    }
    float extra = (tid < 255) ? r[tid * 16 + 16] : 0.0f;
    double acc = 0.0;
    #pragma unroll
    for (int e = 0; e < 16; e++) {
        int d = tid * 16 + e;
        float nxt = (e < 15) ? a[e + 1] : extra;
        if (d < N - 1) acc += fabs((double)nxt - (double)a[e]);
    }
    #pragma unroll
    for (int dd = 32; dd; dd >>= 1) acc += __shfl_down(acc, dd);
    if ((tid & 63) == 0) red[tid >> 6] = acc;
    __syncthreads();
    if (tid == 0) {
        double ds = red[0] + red[1] + red[2] + red[3];
        double xi = 1.0 - 3.0 * ds / ((double)N * (double)N - 1.0);
        out[0] = (float)(-1.0 * xi);  // loss = -WEIGHT * xi
        out[1] = (float)xi;
    }
}

extern "C" void kernel_launch(void* const* d_in, const int* in_sizes, int n_in,
                              void* d_out, int out_size, void* d_ws, size_t ws_size,
                              hipStream_t stream) {
    const float* preds  = (const float*)d_in[0];
    const float* target = (const float*)d_in[1];
    float* out = (float*)d_out;

    char* ws = (char*)d_ws;
    float* y    = (float*)(ws);            // 16 KB
    float* s    = (float*)(ws + 16384);    // 16 KB
    int*   perm = (int*)(ws + 32768);      // 16 KB
    float* r    = (float*)(ws + 49152);    // 16 KB
    float* P    = (float*)(ws + 81920);    // 4 MB

    k_A<<<256, 256, 0, stream>>>(preds, target, y);
    k_B<<<256, 256, 0, stream>>>(y, s, perm);
    k_C<<<256, 256, 0, stream>>>(s, P);
    k_reduce<<<256, 256, 0, stream>>>(P, s, perm, r);
    k_finish2<<<1, 256, 0, stream>>>(r, out);
}